// Round 4
// baseline (1601.201 us; speedup 1.0000x reference)
//
#include <hip/hip_runtime.h>

#define Nn 100000
#define INC 256
#define OC 40
#define GEL 4000000u               // N*40 bf16 elements per g buffer
#define NB 782                     // buckets: src>>7, 128 rows each
#define CAP 7040                   // edges per bucket capacity (mean 6144 + 11 sigma)
#define CHUNK 4096                 // edges per partition block
#define OVFCAP 65536

// ---- workspace layout (bytes) ----
#define MP_OFF   0                       // 131072
#define G_OFF    131072                  // bf16 g1,g2: 16,000,000 B
#define GCUR_OFF 16131072                // NB ints
#define OVFC_OFF (GCUR_OFF + 3128)      // 1 int
#define OVFL_OFF (OVFC_OFF + 8)         // OVFCAP * 12 B
#define PAY_OFF  (OVFL_OFF + OVFCAP*12) // NB*CAP*8 B  (~44 MB) -> total ~61 MB

__device__ __forceinline__ unsigned short f2bf(float f) {
    unsigned b = __float_as_uint(f);
    b += 0x7FFFu + ((b >> 16) & 1u);     // round to nearest even
    return (unsigned short)(b >> 16);
}
__device__ __forceinline__ float bf2f(unsigned short u) {
    return __uint_as_float(((unsigned)u) << 16);
}

// Mp[128][256]: rows j=40*i+o (j<120) = sum_t fc_out_w[o][i*64+t] * fc1_w[t][:]
__global__ void make_M(const float* __restrict__ fc1_w,
                       const float* __restrict__ fc_out_w,
                       float* __restrict__ Mp) {
    int j = blockIdx.x;
    int k = threadIdx.x;
    float acc = 0.f;
    if (j < 120) {
        int i = j / 40, o = j - i * 40;
        const float* wrow = fc_out_w + o * 192 + i * 64;
#pragma unroll 8
        for (int t = 0; t < 64; ++t)
            acc = fmaf(wrow[t], fc1_w[t * 256 + k], acc);
    }
    Mp[j * 256 + k] = acc;
}

// g = x @ Mp^T.  64x128 tile.  cols 0..39 -> out fp32 (+bias); 40..119 -> bf16 g.
__global__ __launch_bounds__(256, 2) void gemm_g(
    const float* __restrict__ x, const float* __restrict__ Mp,
    const float* __restrict__ bias, float* __restrict__ out,
    unsigned short* __restrict__ g) {           // g1 then g2, GEL each
    __shared__ float xs[64 * 65];
    __shared__ float ms[128 * 65];
    const int tid = threadIdx.x;
    const int ty = tid & 15;
    const int tx = tid >> 4;
    const int row0 = blockIdx.x * 64;

    float acc[4][8];
#pragma unroll
    for (int i = 0; i < 4; ++i)
#pragma unroll
        for (int j = 0; j < 8; ++j) acc[i][j] = 0.f;

    for (int kb = 0; kb < INC; kb += 64) {
#pragma unroll
        for (int i = 0; i < 4; ++i) {
            int lin = tid + i * 256;
            int r = lin >> 4;
            int k4 = (lin & 15) << 2;
            float4 v = make_float4(0.f, 0.f, 0.f, 0.f);
            int gr = row0 + r;
            if (gr < Nn) v = *(const float4*)(x + gr * INC + kb + k4);
            float* p = xs + r * 65 + k4;
            p[0] = v.x; p[1] = v.y; p[2] = v.z; p[3] = v.w;
        }
#pragma unroll
        for (int i = 0; i < 8; ++i) {
            int lin = tid + i * 256;
            int r = lin >> 4;
            int k4 = (lin & 15) << 2;
            float4 v = *(const float4*)(Mp + r * 256 + kb + k4);
            float* p = ms + r * 65 + k4;
            p[0] = v.x; p[1] = v.y; p[2] = v.z; p[3] = v.w;
        }
        __syncthreads();
#pragma unroll 8
        for (int k = 0; k < 64; ++k) {
            float a[4], b[8];
#pragma unroll
            for (int i = 0; i < 4; ++i) a[i] = xs[(ty * 4 + i) * 65 + k];
#pragma unroll
            for (int j = 0; j < 8; ++j) b[j] = ms[(tx * 8 + j) * 65 + k];
#pragma unroll
            for (int i = 0; i < 4; ++i)
#pragma unroll
                for (int j = 0; j < 8; ++j)
                    acc[i][j] = fmaf(a[i], b[j], acc[i][j]);
        }
        __syncthreads();
    }

    const int c0 = tx * 8;
    if (c0 < 120) {
        int ib = c0 / 40;
        int o0 = c0 - ib * 40;
        if (ib == 0) {
            float badd[8];
#pragma unroll
            for (int j = 0; j < 8; ++j) badd[j] = bias[o0 + j];
#pragma unroll
            for (int i = 0; i < 4; ++i) {
                int n = row0 + ty * 4 + i;
                if (n < Nn) {
                    float4 v0 = make_float4(acc[i][0] + badd[0], acc[i][1] + badd[1],
                                            acc[i][2] + badd[2], acc[i][3] + badd[3]);
                    float4 v1 = make_float4(acc[i][4] + badd[4], acc[i][5] + badd[5],
                                            acc[i][6] + badd[6], acc[i][7] + badd[7]);
                    *(float4*)(out + n * 40 + o0) = v0;
                    *(float4*)(out + n * 40 + o0 + 4) = v1;
                }
            }
        } else {
            unsigned short* gb = g + (unsigned)(ib - 1) * GEL;
#pragma unroll
            for (int i = 0; i < 4; ++i) {
                int n = row0 + ty * 4 + i;
                if (n < Nn) {
                    ushort4 u0, u1;
                    u0.x = f2bf(acc[i][0]); u0.y = f2bf(acc[i][1]);
                    u0.z = f2bf(acc[i][2]); u0.w = f2bf(acc[i][3]);
                    u1.x = f2bf(acc[i][4]); u1.y = f2bf(acc[i][5]);
                    u1.z = f2bf(acc[i][6]); u1.w = f2bf(acc[i][7]);
                    *(ushort4*)(gb + n * 40 + o0) = u0;
                    *(ushort4*)(gb + n * 40 + o0 + 4) = u1;
                }
            }
        }
    }
}

// Partition 4.8M edges into NB buckets by src>>7, LDS-staged so global payload
// writes are coalesced runs.  payload.x = dst | graph<<17 | (src&127)<<18,
// payload.y = bits(val).  One returning global atomic per (block,bucket).
__global__ __launch_bounds__(512) void partition(
    const int* __restrict__ s1, const int* __restrict__ d1, const float* __restrict__ v1, int E1,
    const int* __restrict__ s2, const int* __restrict__ d2, const float* __restrict__ v2, int E2,
    int* __restrict__ gcur, uint2* __restrict__ payload,
    int* __restrict__ ovf_cnt, unsigned* __restrict__ ovf) {
    __shared__ int cnt[NB];
    __shared__ int loff[NB + 1];
    __shared__ int scanbuf[512];
    __shared__ int gbase[NB];
    __shared__ int lcur[NB];
    __shared__ uint2 pay[CHUNK];
    __shared__ int dest[CHUNK];

    const int t = threadIdx.x;
    const int Etot = E1 + E2;
    const int e0 = blockIdx.x * CHUNK;

    for (int i = t; i < NB; i += 512) cnt[i] = 0;
    __syncthreads();

    int my_s[8]; unsigned my_p[8]; float my_v[8]; bool my_ok[8];
#pragma unroll
    for (int j = 0; j < 8; ++j) {
        int e = e0 + j * 512 + t;
        my_ok[j] = (e < Etot);
        if (my_ok[j]) {
            int s, d; float v; unsigned gbit;
            if (e < E1) { s = s1[e]; d = d1[e]; v = v1[e]; gbit = 0u; }
            else { int e2 = e - E1; s = s2[e2]; d = d2[e2]; v = v2[e2]; gbit = 1u; }
            my_s[j] = s;
            my_p[j] = (unsigned)d | (gbit << 17) | (((unsigned)s & 127u) << 18);
            my_v[j] = v;
            atomicAdd(&cnt[s >> 7], 1);
        }
    }
    __syncthreads();

    // exclusive scan of cnt[NB] -> loff; 2 buckets per thread
    int b0 = t * 2;
    int c0 = (b0 < NB) ? cnt[b0] : 0;
    int c1 = (b0 + 1 < NB) ? cnt[b0 + 1] : 0;
    scanbuf[t] = c0 + c1;
    __syncthreads();
    for (int off = 1; off < 512; off <<= 1) {
        int v = (t >= off) ? scanbuf[t - off] : 0;
        __syncthreads();
        scanbuf[t] += v;
        __syncthreads();
    }
    int ebase = scanbuf[t] - (c0 + c1);
    if (b0 < NB) loff[b0] = ebase;
    if (b0 + 1 < NB) loff[b0 + 1] = ebase + c0;
    if (t == 511) loff[NB] = scanbuf[511];
    __syncthreads();

    for (int i = t; i < NB; i += 512) {
        int c = cnt[i];
        gbase[i] = c ? atomicAdd(&gcur[i], c) : 0;
        lcur[i] = loff[i];
    }
    __syncthreads();

#pragma unroll
    for (int j = 0; j < 8; ++j) {
        if (my_ok[j]) {
            int b = my_s[j] >> 7;
            int lp = atomicAdd(&lcur[b], 1);
            pay[lp] = make_uint2(my_p[j], __float_as_uint(my_v[j]));
            int go = gbase[b] + (lp - loff[b]);
            if (go < CAP) dest[lp] = b * CAP + go;
            else {
                dest[lp] = -1;
                int op = atomicAdd(ovf_cnt, 1);
                if (op < OVFCAP) {
                    ovf[3 * op] = (unsigned)my_s[j];
                    ovf[3 * op + 1] = my_p[j];
                    ovf[3 * op + 2] = __float_as_uint(my_v[j]);
                }
            }
        }
    }
    __syncthreads();

    int tot = loff[NB];
    for (int i = t; i < tot; i += 512) {
        int dd = dest[i];
        if (dd >= 0) payload[dd] = pay[i];
    }
}

// One block per bucket: accumulate 128 rows x 40 ch in LDS (fp32 ds_add),
// then one coalesced out += pass.  No global fp atomics.
__global__ __launch_bounds__(640) void bucket_gather(
    const int* __restrict__ gcur, const uint2* __restrict__ payload,
    const unsigned short* __restrict__ g, float* __restrict__ out) {
    __shared__ float acc[128 * 40];
    const int t = threadIdx.x;
    const int b = blockIdx.x;
    for (int i = t; i < 5120; i += 640) acc[i] = 0.f;
    __syncthreads();

    int n = gcur[b];
    n = (n < CAP) ? n : CAP;
    const int le = t / 10;
    const int q = t - le * 10;
    const uint2* pb = payload + (size_t)b * CAP;

    for (int i0 = 0; i0 < n; i0 += 64) {
        int e = i0 + le;
        if (e < n) {
            uint2 p = pb[e];
            float v = __uint_as_float(p.y);
            unsigned dst = p.x & 0x1FFFFu;
            unsigned gph = (p.x >> 17) & 1u;
            unsigned row = (p.x >> 18) & 127u;
            const unsigned short* gp = g + gph * GEL + dst * 40 + q * 4;
            ushort4 u = *(const ushort4*)gp;
            float* ap = acc + row * 40 + q * 4;
            atomicAdd(ap + 0, v * bf2f(u.x));
            atomicAdd(ap + 1, v * bf2f(u.y));
            atomicAdd(ap + 2, v * bf2f(u.z));
            atomicAdd(ap + 3, v * bf2f(u.w));
        }
    }
    __syncthreads();

    const int row0 = b * 128;
    for (int i = t; i < 5120; i += 640) {
        int r = row0 + i / 40;
        if (r < Nn) out[r * 40 + i % 40] += acc[i];
    }
}

// Slow-path for (expected-zero) bucket overflow.
__global__ __launch_bounds__(256) void ovf_scatter(
    const int* __restrict__ ovf_cnt, const unsigned* __restrict__ ovf,
    const unsigned short* __restrict__ g, float* __restrict__ out) {
    int n = *ovf_cnt;
    n = (n < OVFCAP) ? n : OVFCAP;
    int total = n * 40;
    for (int i = blockIdx.x * 256 + threadIdx.x; i < total; i += 2048) {
        int idx = i / 40, c = i % 40;
        unsigned s = ovf[3 * idx];
        unsigned p = ovf[3 * idx + 1];
        float v = __uint_as_float(ovf[3 * idx + 2]);
        unsigned dst = p & 0x1FFFFu;
        unsigned gph = (p >> 17) & 1u;
        float gf = bf2f(g[gph * GEL + dst * 40 + c]);
        unsafeAtomicAdd(out + s * 40 + c, v * gf);
    }
}

extern "C" void kernel_launch(void* const* d_in, const int* in_sizes, int n_in,
                              void* d_out, int out_size, void* d_ws, size_t ws_size,
                              hipStream_t stream) {
    const float* x        = (const float*)d_in[0];
    const int*   adj_src  = (const int*)d_in[2];
    const int*   adj_dst  = (const int*)d_in[3];
    const float* adj_val  = (const float*)d_in[4];
    const int*   adj2_src = (const int*)d_in[5];
    const int*   adj2_dst = (const int*)d_in[6];
    const float* adj2_val = (const float*)d_in[7];
    const float* fc1_w    = (const float*)d_in[8];
    const float* fc_out_w = (const float*)d_in[9];
    const float* fc_out_b = (const float*)d_in[10];
    float* out = (float*)d_out;

    char* ws = (char*)d_ws;
    float*          Mp      = (float*)(ws + MP_OFF);
    unsigned short* g       = (unsigned short*)(ws + G_OFF);
    int*            gcur    = (int*)(ws + GCUR_OFF);
    int*            ovf_cnt = (int*)(ws + OVFC_OFF);
    unsigned*       ovf     = (unsigned*)(ws + OVFL_OFF);
    uint2*          payload = (uint2*)(ws + PAY_OFF);

    const int E1 = in_sizes[2];
    const int E2 = in_sizes[5];
    const int Etot = E1 + E2;

    make_M<<<128, 256, 0, stream>>>(fc1_w, fc_out_w, Mp);
    gemm_g<<<(Nn + 63) / 64, 256, 0, stream>>>(x, Mp, fc_out_b, out, g);

    hipMemsetAsync(gcur, 0, NB * sizeof(int) + 16, stream);  // gcur + ovf_cnt
    partition<<<(Etot + CHUNK - 1) / CHUNK, 512, 0, stream>>>(
        adj_src, adj_dst, adj_val, E1, adj2_src, adj2_dst, adj2_val, E2,
        gcur, payload, ovf_cnt, ovf);
    bucket_gather<<<NB, 640, 0, stream>>>(gcur, payload, g, out);
    ovf_scatter<<<8, 256, 0, stream>>>(ovf_cnt, ovf, g, out);
}

// Round 5
// 559.551 us; speedup vs baseline: 2.8616x; 2.8616x over previous
//
#include <hip/hip_runtime.h>

#define Nn 100000
#define INC 256
#define OC 40
#define GEL 4000000u               // N*40 bf16 elements per g buffer
#define NB 782                     // buckets: src>>7, 128 rows each
#define CAP 7040                   // edges per bucket capacity (mean 6144 + 11 sigma)
#define CHUNK 4096                 // edges per partition block
#define OVFCAP 65536

// ---- workspace layout (bytes) ----
#define MP_OFF   0                       // 131072
#define G_OFF    131072                  // bf16 g1,g2: 16,000,000 B
#define GCUR_OFF 16131072                // NB ints
#define OVFC_OFF (GCUR_OFF + 3128)      // 1 int
#define OVFL_OFF (OVFC_OFF + 8)         // OVFCAP * 12 B
#define PAY_OFF  (OVFL_OFF + OVFCAP*12) // NB*CAP*8 B  (~44 MB) -> total ~61 MB

__device__ __forceinline__ unsigned short f2bf(float f) {
    unsigned b = __float_as_uint(f);
    b += 0x7FFFu + ((b >> 16) & 1u);     // round to nearest even
    return (unsigned short)(b >> 16);
}
__device__ __forceinline__ float bf2f(unsigned short u) {
    return __uint_as_float(((unsigned)u) << 16);
}

// Mp[128][256]: rows j=40*i+o (j<120) = sum_t fc_out_w[o][i*64+t] * fc1_w[t][:]
__global__ void make_M(const float* __restrict__ fc1_w,
                       const float* __restrict__ fc_out_w,
                       float* __restrict__ Mp) {
    int j = blockIdx.x;
    int k = threadIdx.x;
    float acc = 0.f;
    if (j < 120) {
        int i = j / 40, o = j - i * 40;
        const float* wrow = fc_out_w + o * 192 + i * 64;
#pragma unroll 8
        for (int t = 0; t < 64; ++t)
            acc = fmaf(wrow[t], fc1_w[t * 256 + k], acc);
    }
    Mp[j * 256 + k] = acc;
}

// g = x @ Mp^T.  64x128 tile.  cols 0..39 -> out fp32 (+bias); 40..119 -> bf16 g.
__global__ __launch_bounds__(256, 2) void gemm_g(
    const float* __restrict__ x, const float* __restrict__ Mp,
    const float* __restrict__ bias, float* __restrict__ out,
    unsigned short* __restrict__ g) {           // g1 then g2, GEL each
    __shared__ float xs[64 * 65];
    __shared__ float ms[128 * 65];
    const int tid = threadIdx.x;
    const int ty = tid & 15;
    const int tx = tid >> 4;
    const int row0 = blockIdx.x * 64;

    float acc[4][8];
#pragma unroll
    for (int i = 0; i < 4; ++i)
#pragma unroll
        for (int j = 0; j < 8; ++j) acc[i][j] = 0.f;

    for (int kb = 0; kb < INC; kb += 64) {
#pragma unroll
        for (int i = 0; i < 4; ++i) {
            int lin = tid + i * 256;
            int r = lin >> 4;
            int k4 = (lin & 15) << 2;
            float4 v = make_float4(0.f, 0.f, 0.f, 0.f);
            int gr = row0 + r;
            if (gr < Nn) v = *(const float4*)(x + gr * INC + kb + k4);
            float* p = xs + r * 65 + k4;
            p[0] = v.x; p[1] = v.y; p[2] = v.z; p[3] = v.w;
        }
#pragma unroll
        for (int i = 0; i < 8; ++i) {
            int lin = tid + i * 256;
            int r = lin >> 4;
            int k4 = (lin & 15) << 2;
            float4 v = *(const float4*)(Mp + r * 256 + kb + k4);
            float* p = ms + r * 65 + k4;
            p[0] = v.x; p[1] = v.y; p[2] = v.z; p[3] = v.w;
        }
        __syncthreads();
#pragma unroll 8
        for (int k = 0; k < 64; ++k) {
            float a[4], b[8];
#pragma unroll
            for (int i = 0; i < 4; ++i) a[i] = xs[(ty * 4 + i) * 65 + k];
#pragma unroll
            for (int j = 0; j < 8; ++j) b[j] = ms[(tx * 8 + j) * 65 + k];
#pragma unroll
            for (int i = 0; i < 4; ++i)
#pragma unroll
                for (int j = 0; j < 8; ++j)
                    acc[i][j] = fmaf(a[i], b[j], acc[i][j]);
        }
        __syncthreads();
    }

    const int c0 = tx * 8;
    if (c0 < 120) {
        int ib = c0 / 40;
        int o0 = c0 - ib * 40;
        if (ib == 0) {
            float badd[8];
#pragma unroll
            for (int j = 0; j < 8; ++j) badd[j] = bias[o0 + j];
#pragma unroll
            for (int i = 0; i < 4; ++i) {
                int n = row0 + ty * 4 + i;
                if (n < Nn) {
                    float4 v0 = make_float4(acc[i][0] + badd[0], acc[i][1] + badd[1],
                                            acc[i][2] + badd[2], acc[i][3] + badd[3]);
                    float4 v1 = make_float4(acc[i][4] + badd[4], acc[i][5] + badd[5],
                                            acc[i][6] + badd[6], acc[i][7] + badd[7]);
                    *(float4*)(out + n * 40 + o0) = v0;
                    *(float4*)(out + n * 40 + o0 + 4) = v1;
                }
            }
        } else {
            unsigned short* gb = g + (unsigned)(ib - 1) * GEL;
#pragma unroll
            for (int i = 0; i < 4; ++i) {
                int n = row0 + ty * 4 + i;
                if (n < Nn) {
                    ushort4 u0, u1;
                    u0.x = f2bf(acc[i][0]); u0.y = f2bf(acc[i][1]);
                    u0.z = f2bf(acc[i][2]); u0.w = f2bf(acc[i][3]);
                    u1.x = f2bf(acc[i][4]); u1.y = f2bf(acc[i][5]);
                    u1.z = f2bf(acc[i][6]); u1.w = f2bf(acc[i][7]);
                    *(ushort4*)(gb + n * 40 + o0) = u0;
                    *(ushort4*)(gb + n * 40 + o0 + 4) = u1;
                }
            }
        }
    }
}

// Partition 4.8M edges into NB buckets by src>>7, LDS-staged so global payload
// writes are coalesced runs.  payload.x = dst | graph<<17 | (src&127)<<18,
// payload.y = bits(val).  One returning global atomic per (block,bucket).
__global__ __launch_bounds__(512) void partition(
    const int* __restrict__ s1, const int* __restrict__ d1, const float* __restrict__ v1, int E1,
    const int* __restrict__ s2, const int* __restrict__ d2, const float* __restrict__ v2, int E2,
    int* __restrict__ gcur, uint2* __restrict__ payload,
    int* __restrict__ ovf_cnt, unsigned* __restrict__ ovf) {
    __shared__ int cnt[NB];
    __shared__ int loff[NB + 1];
    __shared__ int scanbuf[512];
    __shared__ int gbase[NB];
    __shared__ int lcur[NB];
    __shared__ uint2 pay[CHUNK];
    __shared__ int dest[CHUNK];

    const int t = threadIdx.x;
    const int Etot = E1 + E2;
    const int e0 = blockIdx.x * CHUNK;

    for (int i = t; i < NB; i += 512) cnt[i] = 0;
    __syncthreads();

    int my_s[8]; unsigned my_p[8]; float my_v[8]; bool my_ok[8];
#pragma unroll
    for (int j = 0; j < 8; ++j) {
        int e = e0 + j * 512 + t;
        my_ok[j] = (e < Etot);
        if (my_ok[j]) {
            int s, d; float v; unsigned gbit;
            if (e < E1) { s = s1[e]; d = d1[e]; v = v1[e]; gbit = 0u; }
            else { int e2 = e - E1; s = s2[e2]; d = d2[e2]; v = v2[e2]; gbit = 1u; }
            my_s[j] = s;
            my_p[j] = (unsigned)d | (gbit << 17) | (((unsigned)s & 127u) << 18);
            my_v[j] = v;
            atomicAdd(&cnt[s >> 7], 1);
        }
    }
    __syncthreads();

    // exclusive scan of cnt[NB] -> loff; 2 buckets per thread
    int b0 = t * 2;
    int c0 = (b0 < NB) ? cnt[b0] : 0;
    int c1 = (b0 + 1 < NB) ? cnt[b0 + 1] : 0;
    scanbuf[t] = c0 + c1;
    __syncthreads();
    for (int off = 1; off < 512; off <<= 1) {
        int v = (t >= off) ? scanbuf[t - off] : 0;
        __syncthreads();
        scanbuf[t] += v;
        __syncthreads();
    }
    int ebase = scanbuf[t] - (c0 + c1);
    if (b0 < NB) loff[b0] = ebase;
    if (b0 + 1 < NB) loff[b0 + 1] = ebase + c0;
    if (t == 511) loff[NB] = scanbuf[511];
    __syncthreads();

    for (int i = t; i < NB; i += 512) {
        int c = cnt[i];
        gbase[i] = c ? atomicAdd(&gcur[i], c) : 0;
        lcur[i] = loff[i];
    }
    __syncthreads();

#pragma unroll
    for (int j = 0; j < 8; ++j) {
        if (my_ok[j]) {
            int b = my_s[j] >> 7;
            int lp = atomicAdd(&lcur[b], 1);
            pay[lp] = make_uint2(my_p[j], __float_as_uint(my_v[j]));
            int go = gbase[b] + (lp - loff[b]);
            if (go < CAP) dest[lp] = b * CAP + go;
            else {
                dest[lp] = -1;
                int op = atomicAdd(ovf_cnt, 1);
                if (op < OVFCAP) {
                    ovf[3 * op] = (unsigned)my_s[j];
                    ovf[3 * op + 1] = my_p[j];
                    ovf[3 * op + 2] = __float_as_uint(my_v[j]);
                }
            }
        }
    }
    __syncthreads();

    int tot = loff[NB];
    for (int i = t; i < tot; i += 512) {
        int dd = dest[i];
        if (dd >= 0) payload[dd] = pay[i];
    }
}

// One block per bucket.  Stage payload in LDS, int-sort by row (count/scan/
// place — int LDS atomics only), then register-accumulated gather: 10 threads
// own each row's 40 channels, one coalesced out+= at the end.  No fp atomics.
__global__ __launch_bounds__(640, 2) void bucket_gather(
    const int* __restrict__ gcur, const uint2* __restrict__ payload,
    const unsigned short* __restrict__ g, float* __restrict__ out) {
    __shared__ uint2 pay[CAP];
    __shared__ unsigned short ord[CAP];
    __shared__ int cnt[128];
    __shared__ int rs[129];
    __shared__ int cur[128];
    __shared__ int sb[128];

    const int t = threadIdx.x;
    const int b = blockIdx.x;
    int n = gcur[b];
    n = (n < CAP) ? n : CAP;

    if (t < 128) cnt[t] = 0;
    __syncthreads();

    // stage + per-row count
    const uint2* pb = payload + (size_t)b * CAP;
    for (int i = t; i < n; i += 640) {
        uint2 p = pb[i];
        pay[i] = p;
        atomicAdd(&cnt[(p.x >> 18) & 127u], 1);
    }
    __syncthreads();

    // exclusive scan of cnt[128] -> rs
    if (t < 128) sb[t] = cnt[t];
    __syncthreads();
    for (int off = 1; off < 128; off <<= 1) {
        int v = 0;
        if (t < 128 && t >= off) v = sb[t - off];
        __syncthreads();
        if (t < 128) sb[t] += v;
        __syncthreads();
    }
    if (t < 128) { int e = sb[t] - cnt[t]; rs[t] = e; cur[t] = e; }
    if (t == 0) rs[128] = n;
    __syncthreads();

    // place: sort edge indices by row
    for (int i = t; i < n; i += 640) {
        int r = (pay[i].x >> 18) & 127;
        int p = atomicAdd(&cur[r], 1);
        ord[p] = (unsigned short)i;
    }
    __syncthreads();

    // gather: 64 row-groups x 10 lanes; 2 passes cover 128 rows
    const int le = t / 10;
    const int q = t - le * 10;
#pragma unroll
    for (int pass = 0; pass < 2; ++pass) {
        int row = pass * 64 + le;
        int e0 = rs[row], e1 = rs[row + 1];
        float4 a = make_float4(0.f, 0.f, 0.f, 0.f);
        for (int e = e0; e < e1; ++e) {
            uint2 p = pay[ord[e]];
            float v = __uint_as_float(p.y);
            unsigned base = (p.x & 0x1FFFFu) * 40u + ((p.x >> 17) & 1u) * GEL;
            ushort4 u = *(const ushort4*)(g + base + q * 4);
            a.x = fmaf(v, bf2f(u.x), a.x);
            a.y = fmaf(v, bf2f(u.y), a.y);
            a.z = fmaf(v, bf2f(u.z), a.z);
            a.w = fmaf(v, bf2f(u.w), a.w);
        }
        int gr = b * 128 + row;
        if (gr < Nn && e1 > e0) {
            float* po = out + gr * 40 + q * 4;
            float4 o = *(float4*)po;
            o.x += a.x; o.y += a.y; o.z += a.z; o.w += a.w;
            *(float4*)po = o;
        }
    }
}

// Slow-path for (expected-zero) bucket overflow.
__global__ __launch_bounds__(256) void ovf_scatter(
    const int* __restrict__ ovf_cnt, const unsigned* __restrict__ ovf,
    const unsigned short* __restrict__ g, float* __restrict__ out) {
    int n = *ovf_cnt;
    n = (n < OVFCAP) ? n : OVFCAP;
    int total = n * 40;
    for (int i = blockIdx.x * 256 + threadIdx.x; i < total; i += 2048) {
        int idx = i / 40, c = i % 40;
        unsigned s = ovf[3 * idx];
        unsigned p = ovf[3 * idx + 1];
        float v = __uint_as_float(ovf[3 * idx + 2]);
        unsigned dst = p & 0x1FFFFu;
        unsigned gph = (p >> 17) & 1u;
        float gf = bf2f(g[gph * GEL + dst * 40 + c]);
        unsafeAtomicAdd(out + s * 40 + c, v * gf);
    }
}

extern "C" void kernel_launch(void* const* d_in, const int* in_sizes, int n_in,
                              void* d_out, int out_size, void* d_ws, size_t ws_size,
                              hipStream_t stream) {
    const float* x        = (const float*)d_in[0];
    const int*   adj_src  = (const int*)d_in[2];
    const int*   adj_dst  = (const int*)d_in[3];
    const float* adj_val  = (const float*)d_in[4];
    const int*   adj2_src = (const int*)d_in[5];
    const int*   adj2_dst = (const int*)d_in[6];
    const float* adj2_val = (const float*)d_in[7];
    const float* fc1_w    = (const float*)d_in[8];
    const float* fc_out_w = (const float*)d_in[9];
    const float* fc_out_b = (const float*)d_in[10];
    float* out = (float*)d_out;

    char* ws = (char*)d_ws;
    float*          Mp      = (float*)(ws + MP_OFF);
    unsigned short* g       = (unsigned short*)(ws + G_OFF);
    int*            gcur    = (int*)(ws + GCUR_OFF);
    int*            ovf_cnt = (int*)(ws + OVFC_OFF);
    unsigned*       ovf     = (unsigned*)(ws + OVFL_OFF);
    uint2*          payload = (uint2*)(ws + PAY_OFF);

    const int E1 = in_sizes[2];
    const int E2 = in_sizes[5];
    const int Etot = E1 + E2;

    make_M<<<128, 256, 0, stream>>>(fc1_w, fc_out_w, Mp);
    gemm_g<<<(Nn + 63) / 64, 256, 0, stream>>>(x, Mp, fc_out_b, out, g);

    hipMemsetAsync(gcur, 0, NB * sizeof(int) + 16, stream);  // gcur + ovf_cnt
    partition<<<(Etot + CHUNK - 1) / CHUNK, 512, 0, stream>>>(
        adj_src, adj_dst, adj_val, E1, adj2_src, adj2_dst, adj2_val, E2,
        gcur, payload, ovf_cnt, ovf);
    bucket_gather<<<NB, 640, 0, stream>>>(gcur, payload, g, out);
    ovf_scatter<<<8, 256, 0, stream>>>(ovf_cnt, ovf, g, out);
}

// Round 6
// 471.606 us; speedup vs baseline: 3.3952x; 1.1865x over previous
//
#include <hip/hip_runtime.h>

#define Nn 100000
#define INC 256
#define OC 40
#define GEL 4000000u               // N*40 bf16 elements per g buffer
#define NB 782                     // buckets: src>>7, 128 rows each
#define CAP 7040                   // edges per bucket capacity (mean 6144 + 11 sigma)
#define CHUNK 4096                 // edges per partition block
#define OVFCAP 65536

// ---- workspace layout (bytes) ----
#define MP_OFF   0                       // 131072
#define G_OFF    131072                  // bf16 g1,g2: 16,000,000 B
#define GCUR_OFF 16131072                // NB ints
#define OVFC_OFF (GCUR_OFF + 3128)      // 1 int
#define OVFL_OFF (OVFC_OFF + 8)         // OVFCAP * 12 B
#define PAY_OFF  (OVFL_OFF + OVFCAP*12) // NB*CAP*8 B  (~44 MB) -> total ~61 MB

__device__ __forceinline__ unsigned short f2bf(float f) {
    unsigned b = __float_as_uint(f);
    b += 0x7FFFu + ((b >> 16) & 1u);     // round to nearest even
    return (unsigned short)(b >> 16);
}
__device__ __forceinline__ float bf2f(unsigned short u) {
    return __uint_as_float(((unsigned)u) << 16);
}

// Mp[128][256]: rows j=40*i+o (j<120) = sum_t fc_out_w[o][i*64+t] * fc1_w[t][:]
__global__ void make_M(const float* __restrict__ fc1_w,
                       const float* __restrict__ fc_out_w,
                       float* __restrict__ Mp) {
    int j = blockIdx.x;
    int k = threadIdx.x;
    float acc = 0.f;
    if (j < 120) {
        int i = j / 40, o = j - i * 40;
        const float* wrow = fc_out_w + o * 192 + i * 64;
#pragma unroll 8
        for (int t = 0; t < 64; ++t)
            acc = fmaf(wrow[t], fc1_w[t * 256 + k], acc);
    }
    Mp[j * 256 + k] = acc;
}

// g = x @ Mp^T.  64x128 tile, K-tile 64.  LDS tiles stored K-major so the
// inner loop reads fragments as 3x ds_read_b128 (36 cyc) vs 64 cyc FMA
// -> VALU-bound (was 12x ds_read_b32 = LDS-issue-bound).
__global__ __launch_bounds__(256, 3) void gemm_g(
    const float* __restrict__ x, const float* __restrict__ Mp,
    const float* __restrict__ bias, float* __restrict__ out,
    unsigned short* __restrict__ g) {           // g1 then g2, GEL each
    __shared__ float xs[64 * 68];    // [k][row], stride 68: a-reads 2-way (free)
    __shared__ float ms[64 * 132];   // [k][col], stride 132: b-reads conflict-free
    const int tid = threadIdx.x;
    const int ty = tid & 15;
    const int tx = tid >> 4;
    const int row0 = blockIdx.x * 64;

    float acc[4][8];
#pragma unroll
    for (int i = 0; i < 4; ++i)
#pragma unroll
        for (int j = 0; j < 8; ++j) acc[i][j] = 0.f;

    for (int kb = 0; kb < INC; kb += 64) {
        // stage x tile transposed: 64 rows x 64 k
#pragma unroll
        for (int i = 0; i < 4; ++i) {
            int lin = tid + i * 256;
            int r = lin >> 4;
            int k4 = (lin & 15) << 2;
            float4 v = make_float4(0.f, 0.f, 0.f, 0.f);
            int gr = row0 + r;
            if (gr < Nn) v = *(const float4*)(x + gr * INC + kb + k4);
            xs[(k4 + 0) * 68 + r] = v.x;
            xs[(k4 + 1) * 68 + r] = v.y;
            xs[(k4 + 2) * 68 + r] = v.z;
            xs[(k4 + 3) * 68 + r] = v.w;
        }
        // stage M tile transposed: 128 cols x 64 k
#pragma unroll
        for (int i = 0; i < 8; ++i) {
            int lin = tid + i * 256;
            int c = lin >> 4;
            int k4 = (lin & 15) << 2;
            float4 v = *(const float4*)(Mp + c * 256 + kb + k4);
            ms[(k4 + 0) * 132 + c] = v.x;
            ms[(k4 + 1) * 132 + c] = v.y;
            ms[(k4 + 2) * 132 + c] = v.z;
            ms[(k4 + 3) * 132 + c] = v.w;
        }
        __syncthreads();
#pragma unroll 4
        for (int k = 0; k < 64; ++k) {
            float4 av  = *(const float4*)(xs + k * 68 + ty * 4);
            float4 bv0 = *(const float4*)(ms + k * 132 + tx * 8);
            float4 bv1 = *(const float4*)(ms + k * 132 + tx * 8 + 4);
            float a[4] = {av.x, av.y, av.z, av.w};
            float bb[8] = {bv0.x, bv0.y, bv0.z, bv0.w, bv1.x, bv1.y, bv1.z, bv1.w};
#pragma unroll
            for (int i = 0; i < 4; ++i)
#pragma unroll
                for (int j = 0; j < 8; ++j)
                    acc[i][j] = fmaf(a[i], bb[j], acc[i][j]);
        }
        __syncthreads();
    }

    const int c0 = tx * 8;
    if (c0 < 120) {
        int ib = c0 / 40;
        int o0 = c0 - ib * 40;
        if (ib == 0) {
            float badd[8];
#pragma unroll
            for (int j = 0; j < 8; ++j) badd[j] = bias[o0 + j];
#pragma unroll
            for (int i = 0; i < 4; ++i) {
                int n = row0 + ty * 4 + i;
                if (n < Nn) {
                    float4 v0 = make_float4(acc[i][0] + badd[0], acc[i][1] + badd[1],
                                            acc[i][2] + badd[2], acc[i][3] + badd[3]);
                    float4 v1 = make_float4(acc[i][4] + badd[4], acc[i][5] + badd[5],
                                            acc[i][6] + badd[6], acc[i][7] + badd[7]);
                    *(float4*)(out + n * 40 + o0) = v0;
                    *(float4*)(out + n * 40 + o0 + 4) = v1;
                }
            }
        } else {
            unsigned short* gb = g + (unsigned)(ib - 1) * GEL;
#pragma unroll
            for (int i = 0; i < 4; ++i) {
                int n = row0 + ty * 4 + i;
                if (n < Nn) {
                    ushort4 u0, u1;
                    u0.x = f2bf(acc[i][0]); u0.y = f2bf(acc[i][1]);
                    u0.z = f2bf(acc[i][2]); u0.w = f2bf(acc[i][3]);
                    u1.x = f2bf(acc[i][4]); u1.y = f2bf(acc[i][5]);
                    u1.z = f2bf(acc[i][6]); u1.w = f2bf(acc[i][7]);
                    *(ushort4*)(gb + n * 40 + o0) = u0;
                    *(ushort4*)(gb + n * 40 + o0 + 4) = u1;
                }
            }
        }
    }
}

// Partition 4.8M edges into NB buckets by src>>7, LDS-staged so global payload
// writes are coalesced runs.  payload.x = dst | graph<<17 | (src&127)<<18,
// payload.y = bits(val).  One returning global atomic per (block,bucket).
__global__ __launch_bounds__(512) void partition(
    const int* __restrict__ s1, const int* __restrict__ d1, const float* __restrict__ v1, int E1,
    const int* __restrict__ s2, const int* __restrict__ d2, const float* __restrict__ v2, int E2,
    int* __restrict__ gcur, uint2* __restrict__ payload,
    int* __restrict__ ovf_cnt, unsigned* __restrict__ ovf) {
    __shared__ int cnt[NB];
    __shared__ int loff[NB + 1];
    __shared__ int scanbuf[512];
    __shared__ int gbase[NB];
    __shared__ int lcur[NB];
    __shared__ uint2 pay[CHUNK];
    __shared__ int dest[CHUNK];

    const int t = threadIdx.x;
    const int Etot = E1 + E2;
    const int e0 = blockIdx.x * CHUNK;

    for (int i = t; i < NB; i += 512) cnt[i] = 0;
    __syncthreads();

    int my_s[8]; unsigned my_p[8]; float my_v[8]; bool my_ok[8];
#pragma unroll
    for (int j = 0; j < 8; ++j) {
        int e = e0 + j * 512 + t;
        my_ok[j] = (e < Etot);
        if (my_ok[j]) {
            int s, d; float v; unsigned gbit;
            if (e < E1) { s = s1[e]; d = d1[e]; v = v1[e]; gbit = 0u; }
            else { int e2 = e - E1; s = s2[e2]; d = d2[e2]; v = v2[e2]; gbit = 1u; }
            my_s[j] = s;
            my_p[j] = (unsigned)d | (gbit << 17) | (((unsigned)s & 127u) << 18);
            my_v[j] = v;
            atomicAdd(&cnt[s >> 7], 1);
        }
    }
    __syncthreads();

    // exclusive scan of cnt[NB] -> loff; 2 buckets per thread
    int b0 = t * 2;
    int c0 = (b0 < NB) ? cnt[b0] : 0;
    int c1 = (b0 + 1 < NB) ? cnt[b0 + 1] : 0;
    scanbuf[t] = c0 + c1;
    __syncthreads();
    for (int off = 1; off < 512; off <<= 1) {
        int v = (t >= off) ? scanbuf[t - off] : 0;
        __syncthreads();
        scanbuf[t] += v;
        __syncthreads();
    }
    int ebase = scanbuf[t] - (c0 + c1);
    if (b0 < NB) loff[b0] = ebase;
    if (b0 + 1 < NB) loff[b0 + 1] = ebase + c0;
    if (t == 511) loff[NB] = scanbuf[511];
    __syncthreads();

    for (int i = t; i < NB; i += 512) {
        int c = cnt[i];
        gbase[i] = c ? atomicAdd(&gcur[i], c) : 0;
        lcur[i] = loff[i];
    }
    __syncthreads();

#pragma unroll
    for (int j = 0; j < 8; ++j) {
        if (my_ok[j]) {
            int b = my_s[j] >> 7;
            int lp = atomicAdd(&lcur[b], 1);
            pay[lp] = make_uint2(my_p[j], __float_as_uint(my_v[j]));
            int go = gbase[b] + (lp - loff[b]);
            if (go < CAP) dest[lp] = b * CAP + go;
            else {
                dest[lp] = -1;
                int op = atomicAdd(ovf_cnt, 1);
                if (op < OVFCAP) {
                    ovf[3 * op] = (unsigned)my_s[j];
                    ovf[3 * op + 1] = my_p[j];
                    ovf[3 * op + 2] = __float_as_uint(my_v[j]);
                }
            }
        }
    }
    __syncthreads();

    int tot = loff[NB];
    for (int i = t; i < tot; i += 512) {
        int dd = dest[i];
        if (dd >= 0) payload[dd] = pay[i];
    }
}

// One block per bucket.  Pass 1: count rows (dword reads of payload.x).
// Pass 2: place payload row-sorted directly into LDS (payload is L2-hot from
// partition).  Gather: 10 lanes own each row's 40 ch, unroll x4 -> 4
// independent global loads in flight; no ord indirection, no fp atomics.
__global__ __launch_bounds__(640, 5) void bucket_gather(
    const int* __restrict__ gcur, const uint2* __restrict__ payload,
    const unsigned short* __restrict__ g, float* __restrict__ out) {
    __shared__ uint2 pay[CAP];       // row-sorted
    __shared__ int cnt[128];
    __shared__ int rs[129];
    __shared__ int cur[128];
    __shared__ int sb[128];

    const int t = threadIdx.x;
    const int b = blockIdx.x;
    int n = gcur[b];
    n = (n < CAP) ? n : CAP;

    if (t < 128) cnt[t] = 0;
    __syncthreads();

    const uint2* pb = payload + (size_t)b * CAP;
    const unsigned* pbx = (const unsigned*)pb;
    for (int i = t; i < n; i += 640)
        atomicAdd(&cnt[(pbx[2 * i] >> 18) & 127u], 1);
    __syncthreads();

    if (t < 128) sb[t] = cnt[t];
    __syncthreads();
    for (int off = 1; off < 128; off <<= 1) {
        int v = 0;
        if (t < 128 && t >= off) v = sb[t - off];
        __syncthreads();
        if (t < 128) sb[t] += v;
        __syncthreads();
    }
    if (t < 128) { int e = sb[t] - cnt[t]; rs[t] = e; cur[t] = e; }
    if (t == 0) rs[128] = n;
    __syncthreads();

    for (int i = t; i < n; i += 640) {
        uint2 p = pb[i];
        int pos = atomicAdd(&cur[(p.x >> 18) & 127u], 1);
        pay[pos] = p;
    }
    __syncthreads();

    const int le = t / 10;
    const int q4 = (t - le * 10) * 4;
#pragma unroll
    for (int pass = 0; pass < 2; ++pass) {
        int row = pass * 64 + le;
        int e0 = rs[row], e1 = rs[row + 1];
        float4 a0 = make_float4(0.f, 0.f, 0.f, 0.f);
        float4 a1 = make_float4(0.f, 0.f, 0.f, 0.f);
        int e = e0;
        for (; e + 4 <= e1; e += 4) {
            uint2 p0 = pay[e], p1 = pay[e + 1], p2 = pay[e + 2], p3 = pay[e + 3];
            ushort4 u0 = *(const ushort4*)(g + (p0.x & 0x1FFFFu) * 40u + ((p0.x >> 17) & 1u) * GEL + q4);
            ushort4 u1 = *(const ushort4*)(g + (p1.x & 0x1FFFFu) * 40u + ((p1.x >> 17) & 1u) * GEL + q4);
            ushort4 u2 = *(const ushort4*)(g + (p2.x & 0x1FFFFu) * 40u + ((p2.x >> 17) & 1u) * GEL + q4);
            ushort4 u3 = *(const ushort4*)(g + (p3.x & 0x1FFFFu) * 40u + ((p3.x >> 17) & 1u) * GEL + q4);
            float v0 = __uint_as_float(p0.y), v1 = __uint_as_float(p1.y);
            float v2 = __uint_as_float(p2.y), v3 = __uint_as_float(p3.y);
            a0.x = fmaf(v0, bf2f(u0.x), a0.x); a0.y = fmaf(v0, bf2f(u0.y), a0.y);
            a0.z = fmaf(v0, bf2f(u0.z), a0.z); a0.w = fmaf(v0, bf2f(u0.w), a0.w);
            a1.x = fmaf(v1, bf2f(u1.x), a1.x); a1.y = fmaf(v1, bf2f(u1.y), a1.y);
            a1.z = fmaf(v1, bf2f(u1.z), a1.z); a1.w = fmaf(v1, bf2f(u1.w), a1.w);
            a0.x = fmaf(v2, bf2f(u2.x), a0.x); a0.y = fmaf(v2, bf2f(u2.y), a0.y);
            a0.z = fmaf(v2, bf2f(u2.z), a0.z); a0.w = fmaf(v2, bf2f(u2.w), a0.w);
            a1.x = fmaf(v3, bf2f(u3.x), a1.x); a1.y = fmaf(v3, bf2f(u3.y), a1.y);
            a1.z = fmaf(v3, bf2f(u3.z), a1.z); a1.w = fmaf(v3, bf2f(u3.w), a1.w);
        }
        for (; e < e1; ++e) {
            uint2 p = pay[e];
            float v = __uint_as_float(p.y);
            ushort4 u = *(const ushort4*)(g + (p.x & 0x1FFFFu) * 40u + ((p.x >> 17) & 1u) * GEL + q4);
            a0.x = fmaf(v, bf2f(u.x), a0.x); a0.y = fmaf(v, bf2f(u.y), a0.y);
            a0.z = fmaf(v, bf2f(u.z), a0.z); a0.w = fmaf(v, bf2f(u.w), a0.w);
        }
        int gr = b * 128 + row;
        if (gr < Nn && e1 > e0) {
            float* po = out + gr * 40 + q4;
            float4 o = *(float4*)po;
            o.x += a0.x + a1.x; o.y += a0.y + a1.y;
            o.z += a0.z + a1.z; o.w += a0.w + a1.w;
            *(float4*)po = o;
        }
    }
}

// Slow-path for (expected-zero) bucket overflow.
__global__ __launch_bounds__(256) void ovf_scatter(
    const int* __restrict__ ovf_cnt, const unsigned* __restrict__ ovf,
    const unsigned short* __restrict__ g, float* __restrict__ out) {
    int n = *ovf_cnt;
    n = (n < OVFCAP) ? n : OVFCAP;
    int total = n * 40;
    for (int i = blockIdx.x * 256 + threadIdx.x; i < total; i += 2048) {
        int idx = i / 40, c = i % 40;
        unsigned s = ovf[3 * idx];
        unsigned p = ovf[3 * idx + 1];
        float v = __uint_as_float(ovf[3 * idx + 2]);
        unsigned dst = p & 0x1FFFFu;
        unsigned gph = (p >> 17) & 1u;
        float gf = bf2f(g[gph * GEL + dst * 40 + c]);
        unsafeAtomicAdd(out + s * 40 + c, v * gf);
    }
}

extern "C" void kernel_launch(void* const* d_in, const int* in_sizes, int n_in,
                              void* d_out, int out_size, void* d_ws, size_t ws_size,
                              hipStream_t stream) {
    const float* x        = (const float*)d_in[0];
    const int*   adj_src  = (const int*)d_in[2];
    const int*   adj_dst  = (const int*)d_in[3];
    const float* adj_val  = (const float*)d_in[4];
    const int*   adj2_src = (const int*)d_in[5];
    const int*   adj2_dst = (const int*)d_in[6];
    const float* adj2_val = (const float*)d_in[7];
    const float* fc1_w    = (const float*)d_in[8];
    const float* fc_out_w = (const float*)d_in[9];
    const float* fc_out_b = (const float*)d_in[10];
    float* out = (float*)d_out;

    char* ws = (char*)d_ws;
    float*          Mp      = (float*)(ws + MP_OFF);
    unsigned short* g       = (unsigned short*)(ws + G_OFF);
    int*            gcur    = (int*)(ws + GCUR_OFF);
    int*            ovf_cnt = (int*)(ws + OVFC_OFF);
    unsigned*       ovf     = (unsigned*)(ws + OVFL_OFF);
    uint2*          payload = (uint2*)(ws + PAY_OFF);

    const int E1 = in_sizes[2];
    const int E2 = in_sizes[5];
    const int Etot = E1 + E2;

    make_M<<<128, 256, 0, stream>>>(fc1_w, fc_out_w, Mp);
    gemm_g<<<(Nn + 63) / 64, 256, 0, stream>>>(x, Mp, fc_out_b, out, g);

    hipMemsetAsync(gcur, 0, NB * sizeof(int) + 16, stream);  // gcur + ovf_cnt
    partition<<<(Etot + CHUNK - 1) / CHUNK, 512, 0, stream>>>(
        adj_src, adj_dst, adj_val, E1, adj2_src, adj2_dst, adj2_val, E2,
        gcur, payload, ovf_cnt, ovf);
    bucket_gather<<<NB, 640, 0, stream>>>(gcur, payload, g, out);
    ovf_scatter<<<8, 256, 0, stream>>>(ovf_cnt, ovf, g, out);
}

// Round 7
// 407.326 us; speedup vs baseline: 3.9310x; 1.1578x over previous
//
#include <hip/hip_runtime.h>

#define Nn 100000
#define INC 256
#define OC 40
#define GEL 4000000u               // N*40 bf16 elements per g buffer
#define NB 782                     // buckets: src>>7, 128 rows each
#define CAP 7040                   // edges per bucket capacity
#define CHUNK 4096                 // edges per partition block
#define OVFCAP 65536
#define BSTRIDE 264                // LDS stride (bf16 el) for M tile: conflict-free b-frag reads

// ---- workspace layout (bytes) ----
#define MP_OFF   0                       // bf16 M: 128*256*2 = 65536 (slot 131072)
#define G_OFF    131072                  // bf16 g1,g2: 16,000,000 B
#define GCUR_OFF 16131072                // NB ints
#define OVFC_OFF (GCUR_OFF + 3128)      // 1 int
#define OVFL_OFF (OVFC_OFF + 8)         // OVFCAP * 12 B
#define PAY_OFF  (OVFL_OFF + OVFCAP*12) // NB*CAP*8 B

typedef __attribute__((ext_vector_type(8))) short bf16x8;
typedef __attribute__((ext_vector_type(4))) float f32x4;

__device__ __forceinline__ unsigned short f2bf(float f) {
    unsigned b = __float_as_uint(f);
    b += 0x7FFFu + ((b >> 16) & 1u);     // RNE
    return (unsigned short)(b >> 16);
}
__device__ __forceinline__ float bf2f(unsigned short u) {
    return __uint_as_float(((unsigned)u) << 16);
}

// Mb[128][256] bf16: rows j=40*i+o (j<120) = sum_t fc_out_w[o][i*64+t]*fc1_w[t][:]
__global__ void make_M(const float* __restrict__ fc1_w,
                       const float* __restrict__ fc_out_w,
                       unsigned short* __restrict__ Mb) {
    int j = blockIdx.x;   // 0..127
    int k = threadIdx.x;  // 0..255
    float acc = 0.f;
    if (j < 120) {
        int i = j / 40, o = j - i * 40;
        const float* wrow = fc_out_w + o * 192 + i * 64;
#pragma unroll 8
        for (int t = 0; t < 64; ++t)
            acc = fmaf(wrow[t], fc1_w[t * 256 + k], acc);
    }
    Mb[j * 256 + k] = (j < 120) ? f2bf(acc) : (unsigned short)0;
}

// MFMA bf16 GEMM: block = 64 rows x 120 cols, 4 waves (16 rows each).
// B (bf16 M) staged once in LDS (no inner barriers); A-frags load direct
// global->reg (verified layout A[m=lane&15][k=quad*8+j]), pipelined 1 kt ahead.
// D layout (verified): col=lane&15, row=quad*4+reg.
__global__ __launch_bounds__(256, 2) void gemm_mfma(
    const float* __restrict__ x, const unsigned short* __restrict__ Mb,
    const float* __restrict__ bias, float* __restrict__ out,
    unsigned short* __restrict__ g) {
    __shared__ unsigned short mlds[120 * BSTRIDE];
    const int tid = threadIdx.x;
    const int w = tid >> 6;
    const int l = tid & 63;
    const int lane15 = l & 15;
    const int quad = l >> 4;

    // stage B: 120 rows x 256 k, 8 bf16 per slot
    for (int i = tid; i < 3840; i += 256) {
        int r = i >> 5;
        int k8 = (i & 31) * 8;
        uint4 v = *(const uint4*)(Mb + r * 256 + k8);
        *(uint4*)(mlds + r * BSTRIDE + k8) = v;
    }
    __syncthreads();

    const int arow = blockIdx.x * 64 + w * 16 + lane15;
    const bool rok = arow < Nn;
    const float* xp = x + (size_t)arow * INC + quad * 8;

    f32x4 acc[8];
#pragma unroll
    for (int c = 0; c < 8; ++c) acc[c] = (f32x4){0.f, 0.f, 0.f, 0.f};

    float4 c0 = make_float4(0, 0, 0, 0), c1 = make_float4(0, 0, 0, 0);
    if (rok) { c0 = *(const float4*)(xp); c1 = *(const float4*)(xp + 4); }

#pragma unroll
    for (int kt = 0; kt < 8; ++kt) {
        float4 n0 = make_float4(0, 0, 0, 0), n1 = make_float4(0, 0, 0, 0);
        if (kt < 7 && rok) {
            n0 = *(const float4*)(xp + (kt + 1) * 32);
            n1 = *(const float4*)(xp + (kt + 1) * 32 + 4);
        }
        bf16x8 af;
        af[0] = (short)f2bf(c0.x); af[1] = (short)f2bf(c0.y);
        af[2] = (short)f2bf(c0.z); af[3] = (short)f2bf(c0.w);
        af[4] = (short)f2bf(c1.x); af[5] = (short)f2bf(c1.y);
        af[6] = (short)f2bf(c1.z); af[7] = (short)f2bf(c1.w);
        const unsigned short* bbase = mlds + kt * 32 + quad * 8 + lane15 * BSTRIDE;
#pragma unroll
        for (int ct = 0; ct < 8; ++ct) {
            if (ct * 16 >= 120) break;   // ct=7 covers cols 112..127 (120..127 discarded later)
            bf16x8 bf = *(const bf16x8*)(bbase + ct * 16 * BSTRIDE);
            acc[ct] = __builtin_amdgcn_mfma_f32_16x16x32_bf16(af, bf, acc[ct], 0, 0, 0);
        }
        c0 = n0; c1 = n1;
    }

    // epilogue
#pragma unroll
    for (int ct = 0; ct < 8; ++ct) {
        int col = ct * 16 + lane15;
        if (col >= 120) continue;
        int ib = col / 40;
        int cc = col - ib * 40;
        float badd = (ib == 0) ? bias[cc] : 0.f;
#pragma unroll
        for (int reg = 0; reg < 4; ++reg) {
            int gr = blockIdx.x * 64 + w * 16 + quad * 4 + reg;
            if (gr >= Nn) continue;
            float v = acc[ct][reg] + badd;
            if (ib == 0) out[gr * 40 + cc] = v;
            else g[(unsigned)(ib - 1) * GEL + (unsigned)gr * 40u + cc] = f2bf(v);
        }
    }
}

// Partition 4.8M edges into NB buckets by src>>7, LDS-staged coalesced runs.
// payload.x = dst | graph<<17 | (src&127)<<18, payload.y = bits(val).
__global__ __launch_bounds__(512) void partition(
    const int* __restrict__ s1, const int* __restrict__ d1, const float* __restrict__ v1, int E1,
    const int* __restrict__ s2, const int* __restrict__ d2, const float* __restrict__ v2, int E2,
    int* __restrict__ gcur, uint2* __restrict__ payload,
    int* __restrict__ ovf_cnt, unsigned* __restrict__ ovf) {
    __shared__ int cnt[NB];
    __shared__ int loff[NB + 1];
    __shared__ int scanbuf[512];
    __shared__ int gbase[NB];
    __shared__ int lcur[NB];
    __shared__ uint2 pay[CHUNK];
    __shared__ int dest[CHUNK];

    const int t = threadIdx.x;
    const int Etot = E1 + E2;
    const int e0 = blockIdx.x * CHUNK;

    for (int i = t; i < NB; i += 512) cnt[i] = 0;
    __syncthreads();

    int my_s[8]; unsigned my_p[8]; float my_v[8]; bool my_ok[8];
#pragma unroll
    for (int j = 0; j < 8; ++j) {
        int e = e0 + j * 512 + t;
        my_ok[j] = (e < Etot);
        if (my_ok[j]) {
            int s, d; float v; unsigned gbit;
            if (e < E1) { s = s1[e]; d = d1[e]; v = v1[e]; gbit = 0u; }
            else { int e2 = e - E1; s = s2[e2]; d = d2[e2]; v = v2[e2]; gbit = 1u; }
            my_s[j] = s;
            my_p[j] = (unsigned)d | (gbit << 17) | (((unsigned)s & 127u) << 18);
            my_v[j] = v;
            atomicAdd(&cnt[s >> 7], 1);
        }
    }
    __syncthreads();

    int b0 = t * 2;
    int c0 = (b0 < NB) ? cnt[b0] : 0;
    int c1 = (b0 + 1 < NB) ? cnt[b0 + 1] : 0;
    scanbuf[t] = c0 + c1;
    __syncthreads();
    for (int off = 1; off < 512; off <<= 1) {
        int v = (t >= off) ? scanbuf[t - off] : 0;
        __syncthreads();
        scanbuf[t] += v;
        __syncthreads();
    }
    int ebase = scanbuf[t] - (c0 + c1);
    if (b0 < NB) loff[b0] = ebase;
    if (b0 + 1 < NB) loff[b0 + 1] = ebase + c0;
    if (t == 511) loff[NB] = scanbuf[511];
    __syncthreads();

    for (int i = t; i < NB; i += 512) {
        int c = cnt[i];
        gbase[i] = c ? atomicAdd(&gcur[i], c) : 0;
        lcur[i] = loff[i];
    }
    __syncthreads();

#pragma unroll
    for (int j = 0; j < 8; ++j) {
        if (my_ok[j]) {
            int b = my_s[j] >> 7;
            int lp = atomicAdd(&lcur[b], 1);
            pay[lp] = make_uint2(my_p[j], __float_as_uint(my_v[j]));
            int go = gbase[b] + (lp - loff[b]);
            if (go < CAP) dest[lp] = b * CAP + go;
            else {
                dest[lp] = -1;
                int op = atomicAdd(ovf_cnt, 1);
                if (op < OVFCAP) {
                    ovf[3 * op] = (unsigned)my_s[j];
                    ovf[3 * op + 1] = my_p[j];
                    ovf[3 * op + 2] = __float_as_uint(my_v[j]);
                }
            }
        }
    }
    __syncthreads();

    int tot = loff[NB];
    for (int i = t; i < tot; i += 512) {
        int dd = dest[i];
        if (dd >= 0) payload[dd] = pay[i];
    }
}

// One block per bucket.  Count rows -> scan -> place row-sorted PACKED entries
// (dst|graph | val quantized to 14-bit) into a uint32 LDS array (28 KB ->
// 3 blocks/CU vs R6's 2).  Hot loop: b32 broadcast + unrolled x4 gathers.
__global__ __launch_bounds__(640, 7) void bucket_gather(
    const int* __restrict__ gcur, const uint2* __restrict__ payload,
    const unsigned short* __restrict__ g, float* __restrict__ out) {
    __shared__ unsigned spay[CAP];
    __shared__ int cnt[128];
    __shared__ int rs[129];
    __shared__ int cur[128];
    __shared__ int sb[128];

    const int t = threadIdx.x;
    const int b = blockIdx.x;
    int n = gcur[b];
    n = (n < CAP) ? n : CAP;

    if (t < 128) cnt[t] = 0;
    __syncthreads();

    const uint2* pb = payload + (size_t)b * CAP;
    const unsigned* pbx = (const unsigned*)pb;
    for (int i = t; i < n; i += 640)
        atomicAdd(&cnt[(pbx[2 * i] >> 18) & 127u], 1);
    __syncthreads();

    if (t < 128) sb[t] = cnt[t];
    __syncthreads();
    for (int off = 1; off < 128; off <<= 1) {
        int v = 0;
        if (t < 128 && t >= off) v = sb[t - off];
        __syncthreads();
        if (t < 128) sb[t] += v;
        __syncthreads();
    }
    if (t < 128) { int e = sb[t] - cnt[t]; rs[t] = e; cur[t] = e; }
    if (t == 0) rs[128] = n;
    __syncthreads();

    for (int i = t; i < n; i += 640) {
        uint2 p = pb[i];
        unsigned q = (unsigned)(__uint_as_float(p.y) * 16383.f + 0.5f);
        int pos = atomicAdd(&cur[(p.x >> 18) & 127u], 1);
        spay[pos] = (p.x & 0x3FFFFu) | (q << 18);
    }
    __syncthreads();

    const int le = t / 10;
    const int q4 = (t - le * 10) * 4;
    const float VS = 1.0f / 16383.0f;
#pragma unroll
    for (int pass = 0; pass < 2; ++pass) {
        int row = pass * 64 + le;
        int e0 = rs[row], e1 = rs[row + 1];
        float4 a0 = make_float4(0.f, 0.f, 0.f, 0.f);
        float4 a1 = make_float4(0.f, 0.f, 0.f, 0.f);
        int e = e0;
        for (; e + 4 <= e1; e += 4) {
            unsigned p0 = spay[e], p1 = spay[e + 1], p2 = spay[e + 2], p3 = spay[e + 3];
            ushort4 u0 = *(const ushort4*)(g + (p0 & 0x1FFFFu) * 40u + ((p0 >> 17) & 1u) * GEL + q4);
            ushort4 u1 = *(const ushort4*)(g + (p1 & 0x1FFFFu) * 40u + ((p1 >> 17) & 1u) * GEL + q4);
            ushort4 u2 = *(const ushort4*)(g + (p2 & 0x1FFFFu) * 40u + ((p2 >> 17) & 1u) * GEL + q4);
            ushort4 u3 = *(const ushort4*)(g + (p3 & 0x1FFFFu) * 40u + ((p3 >> 17) & 1u) * GEL + q4);
            float v0 = (float)(p0 >> 18) * VS, v1 = (float)(p1 >> 18) * VS;
            float v2 = (float)(p2 >> 18) * VS, v3 = (float)(p3 >> 18) * VS;
            a0.x = fmaf(v0, bf2f(u0.x), a0.x); a0.y = fmaf(v0, bf2f(u0.y), a0.y);
            a0.z = fmaf(v0, bf2f(u0.z), a0.z); a0.w = fmaf(v0, bf2f(u0.w), a0.w);
            a1.x = fmaf(v1, bf2f(u1.x), a1.x); a1.y = fmaf(v1, bf2f(u1.y), a1.y);
            a1.z = fmaf(v1, bf2f(u1.z), a1.z); a1.w = fmaf(v1, bf2f(u1.w), a1.w);
            a0.x = fmaf(v2, bf2f(u2.x), a0.x); a0.y = fmaf(v2, bf2f(u2.y), a0.y);
            a0.z = fmaf(v2, bf2f(u2.z), a0.z); a0.w = fmaf(v2, bf2f(u2.w), a0.w);
            a1.x = fmaf(v3, bf2f(u3.x), a1.x); a1.y = fmaf(v3, bf2f(u3.y), a1.y);
            a1.z = fmaf(v3, bf2f(u3.z), a1.z); a1.w = fmaf(v3, bf2f(u3.w), a1.w);
        }
        for (; e < e1; ++e) {
            unsigned p = spay[e];
            float v = (float)(p >> 18) * VS;
            ushort4 u = *(const ushort4*)(g + (p & 0x1FFFFu) * 40u + ((p >> 17) & 1u) * GEL + q4);
            a0.x = fmaf(v, bf2f(u.x), a0.x); a0.y = fmaf(v, bf2f(u.y), a0.y);
            a0.z = fmaf(v, bf2f(u.z), a0.z); a0.w = fmaf(v, bf2f(u.w), a0.w);
        }
        int gr = b * 128 + row;
        if (gr < Nn && e1 > e0) {
            float* po = out + gr * 40 + q4;
            float4 o = *(float4*)po;
            o.x += a0.x + a1.x; o.y += a0.y + a1.y;
            o.z += a0.z + a1.z; o.w += a0.w + a1.w;
            *(float4*)po = o;
        }
    }
}

// Slow-path for (expected-zero) bucket overflow.
__global__ __launch_bounds__(256) void ovf_scatter(
    const int* __restrict__ ovf_cnt, const unsigned* __restrict__ ovf,
    const unsigned short* __restrict__ g, float* __restrict__ out) {
    int n = *ovf_cnt;
    n = (n < OVFCAP) ? n : OVFCAP;
    int total = n * 40;
    for (int i = blockIdx.x * 256 + threadIdx.x; i < total; i += 2048) {
        int idx = i / 40, c = i % 40;
        unsigned s = ovf[3 * idx];
        unsigned p = ovf[3 * idx + 1];
        float v = __uint_as_float(ovf[3 * idx + 2]);
        unsigned dst = p & 0x1FFFFu;
        unsigned gph = (p >> 17) & 1u;
        float gf = bf2f(g[gph * GEL + dst * 40 + c]);
        unsafeAtomicAdd(out + s * 40 + c, v * gf);
    }
}

extern "C" void kernel_launch(void* const* d_in, const int* in_sizes, int n_in,
                              void* d_out, int out_size, void* d_ws, size_t ws_size,
                              hipStream_t stream) {
    const float* x        = (const float*)d_in[0];
    const int*   adj_src  = (const int*)d_in[2];
    const int*   adj_dst  = (const int*)d_in[3];
    const float* adj_val  = (const float*)d_in[4];
    const int*   adj2_src = (const int*)d_in[5];
    const int*   adj2_dst = (const int*)d_in[6];
    const float* adj2_val = (const float*)d_in[7];
    const float* fc1_w    = (const float*)d_in[8];
    const float* fc_out_w = (const float*)d_in[9];
    const float* fc_out_b = (const float*)d_in[10];
    float* out = (float*)d_out;

    char* ws = (char*)d_ws;
    unsigned short* Mb      = (unsigned short*)(ws + MP_OFF);
    unsigned short* g       = (unsigned short*)(ws + G_OFF);
    int*            gcur    = (int*)(ws + GCUR_OFF);
    int*            ovf_cnt = (int*)(ws + OVFC_OFF);
    unsigned*       ovf     = (unsigned*)(ws + OVFL_OFF);
    uint2*          payload = (uint2*)(ws + PAY_OFF);

    const int E1 = in_sizes[2];
    const int E2 = in_sizes[5];
    const int Etot = E1 + E2;

    make_M<<<128, 256, 0, stream>>>(fc1_w, fc_out_w, Mb);
    gemm_mfma<<<(Nn + 63) / 64, 256, 0, stream>>>(x, Mb, fc_out_b, out, g);

    hipMemsetAsync(gcur, 0, NB * sizeof(int) + 16, stream);  // gcur + ovf_cnt
    partition<<<(Etot + CHUNK - 1) / CHUNK, 512, 0, stream>>>(
        adj_src, adj_dst, adj_val, E1, adj2_src, adj2_dst, adj2_val, E2,
        gcur, payload, ovf_cnt, ovf);
    bucket_gather<<<NB, 640, 0, stream>>>(gcur, payload, g, out);
    ovf_scatter<<<8, 256, 0, stream>>>(ovf_cnt, ovf, g, out);
}

// Round 8
// 395.410 us; speedup vs baseline: 4.0495x; 1.0301x over previous
//
#include <hip/hip_runtime.h>

#define Nn 100000
#define INC 256
#define OC 40
#define GEL 4000000u               // N*40 bf16 elements per g buffer
#define NB 782                     // buckets: src>>7, 128 rows each
#define CAP 7040                   // edges per bucket capacity
#define CAPH 3744                  // half-bucket (64-row) capacity in gather
#define CHUNK 4096                 // edges per partition block
#define OVFCAP 65536
#define BSTRIDE 264                // LDS stride (bf16) for M tile

// ---- workspace layout (bytes) ----
#define MP_OFF   0                       // bf16 M: 128*256*2 = 65536 (slot 131072)
#define G_OFF    131072                  // bf16 g1,g2: 16,000,000 B
#define GCUR_OFF 16131072                // NB ints
#define OVFC_OFF (GCUR_OFF + 3128)      // 1 int
#define OVFL_OFF (OVFC_OFF + 8)         // OVFCAP * 12 B
#define PAY_OFF  (OVFL_OFF + OVFCAP*12) // NB*CAP*8 B

typedef __attribute__((ext_vector_type(8))) short bf16x8;
typedef __attribute__((ext_vector_type(4))) float f32x4;

__device__ __forceinline__ unsigned short f2bf(float f) {
    unsigned b = __float_as_uint(f);
    b += 0x7FFFu + ((b >> 16) & 1u);     // RNE
    return (unsigned short)(b >> 16);
}
__device__ __forceinline__ float bf2f(unsigned short u) {
    return __uint_as_float(((unsigned)u) << 16);
}

// Mb[128][256] bf16
__global__ void make_M(const float* __restrict__ fc1_w,
                       const float* __restrict__ fc_out_w,
                       unsigned short* __restrict__ Mb) {
    int j = blockIdx.x;   // 0..127
    int k = threadIdx.x;  // 0..255
    float acc = 0.f;
    if (j < 120) {
        int i = j / 40, o = j - i * 40;
        const float* wrow = fc_out_w + o * 192 + i * 64;
#pragma unroll 8
        for (int t = 0; t < 64; ++t)
            acc = fmaf(wrow[t], fc1_w[t * 256 + k], acc);
    }
    Mb[j * 256 + k] = (j < 120) ? f2bf(acc) : (unsigned short)0;
}

// MFMA bf16 GEMM: block = 128 rows x 120 cols, 8 waves (16 rows each).
// 512-thread blocks -> 2 blocks/CU (126 KB LDS) = 16 waves/CU (R7 had 8).
// Prefetch depth 2 on the A-stream.
__global__ __launch_bounds__(512, 4) void gemm_mfma(
    const float* __restrict__ x, const unsigned short* __restrict__ Mb,
    const float* __restrict__ bias, float* __restrict__ out,
    unsigned short* __restrict__ g) {
    __shared__ unsigned short mlds[120 * BSTRIDE];
    const int tid = threadIdx.x;
    const int w = tid >> 6;
    const int l = tid & 63;
    const int lane15 = l & 15;
    const int quad = l >> 4;

    for (int i = tid; i < 3840; i += 512) {
        int r = i >> 5;
        int k8 = (i & 31) * 8;
        uint4 v = *(const uint4*)(Mb + r * 256 + k8);
        *(uint4*)(mlds + r * BSTRIDE + k8) = v;
    }
    __syncthreads();

    const int arow = blockIdx.x * 128 + w * 16 + lane15;
    const bool rok = arow < Nn;
    const float* xp = x + (size_t)arow * INC + quad * 8;

    f32x4 acc[8];
#pragma unroll
    for (int c = 0; c < 8; ++c) acc[c] = (f32x4){0.f, 0.f, 0.f, 0.f};

    float4 pa[3], pb_[3];
#pragma unroll
    for (int p = 0; p < 2; ++p) {
        pa[p] = make_float4(0, 0, 0, 0); pb_[p] = make_float4(0, 0, 0, 0);
        if (rok) { pa[p] = *(const float4*)(xp + p * 32); pb_[p] = *(const float4*)(xp + p * 32 + 4); }
    }

#pragma unroll
    for (int kt = 0; kt < 8; ++kt) {
        const int nb = (kt + 2) % 3;
        if (kt + 2 < 8) {
            pa[nb] = make_float4(0, 0, 0, 0); pb_[nb] = make_float4(0, 0, 0, 0);
            if (rok) {
                pa[nb] = *(const float4*)(xp + (kt + 2) * 32);
                pb_[nb] = *(const float4*)(xp + (kt + 2) * 32 + 4);
            }
        }
        const int cu = kt % 3;
        bf16x8 af;
        af[0] = (short)f2bf(pa[cu].x); af[1] = (short)f2bf(pa[cu].y);
        af[2] = (short)f2bf(pa[cu].z); af[3] = (short)f2bf(pa[cu].w);
        af[4] = (short)f2bf(pb_[cu].x); af[5] = (short)f2bf(pb_[cu].y);
        af[6] = (short)f2bf(pb_[cu].z); af[7] = (short)f2bf(pb_[cu].w);
        const unsigned short* bbase = mlds + kt * 32 + quad * 8 + lane15 * BSTRIDE;
#pragma unroll
        for (int ct = 0; ct < 8; ++ct) {
            if (ct * 16 >= 120) break;
            bf16x8 bf = *(const bf16x8*)(bbase + ct * 16 * BSTRIDE);
            acc[ct] = __builtin_amdgcn_mfma_f32_16x16x32_bf16(af, bf, acc[ct], 0, 0, 0);
        }
    }

#pragma unroll
    for (int ct = 0; ct < 8; ++ct) {
        int col = ct * 16 + lane15;
        if (col >= 120) continue;
        int ib = col / 40;
        int cc = col - ib * 40;
        float badd = (ib == 0) ? bias[cc] : 0.f;
#pragma unroll
        for (int reg = 0; reg < 4; ++reg) {
            int gr = blockIdx.x * 128 + w * 16 + quad * 4 + reg;
            if (gr >= Nn) continue;
            float v = acc[ct][reg] + badd;
            if (ib == 0) out[gr * 40 + cc] = v;
            else g[(unsigned)(ib - 1) * GEL + (unsigned)gr * 40u + cc] = f2bf(v);
        }
    }
}

// Partition: 1024-thread blocks (16 waves -> 32 waves/CU at 2 blocks), one
// LDS atomic per edge (rank returned by the counting atomic), ushort dest ids.
__global__ __launch_bounds__(1024, 8) void partition(
    const int* __restrict__ s1, const int* __restrict__ d1, const float* __restrict__ v1, int E1,
    const int* __restrict__ s2, const int* __restrict__ d2, const float* __restrict__ v2, int E2,
    int* __restrict__ gcur, uint2* __restrict__ payload,
    int* __restrict__ ovf_cnt, unsigned* __restrict__ ovf) {
    __shared__ int cnt[NB];
    __shared__ int loff[NB + 1];
    __shared__ int gbase[NB];
    __shared__ int scanbuf[1024];
    __shared__ uint2 pay[CHUNK];
    __shared__ unsigned short dest16[CHUNK];

    const int t = threadIdx.x;
    const int Etot = E1 + E2;
    const int e0 = blockIdx.x * CHUNK;

    for (int i = t; i < NB; i += 1024) cnt[i] = 0;
    __syncthreads();

    int my_b[4]; int my_rank[4]; unsigned my_p[4]; float my_v[4]; bool my_ok[4];
#pragma unroll
    for (int j = 0; j < 4; ++j) {
        int e = e0 + j * 1024 + t;
        my_ok[j] = (e < Etot);
        if (my_ok[j]) {
            int s, d; float v; unsigned gbit;
            if (e < E1) { s = s1[e]; d = d1[e]; v = v1[e]; gbit = 0u; }
            else { int e2 = e - E1; s = s2[e2]; d = d2[e2]; v = v2[e2]; gbit = 1u; }
            my_b[j] = s >> 7;
            my_p[j] = (unsigned)d | (gbit << 17) | (((unsigned)s & 127u) << 18);
            my_v[j] = v;
            my_rank[j] = atomicAdd(&cnt[my_b[j]], 1);
        }
    }
    __syncthreads();

    // exclusive scan of cnt[NB] (NB < 1024)
    int c = (t < NB) ? cnt[t] : 0;
    scanbuf[t] = c;
    __syncthreads();
    for (int off = 1; off < 1024; off <<= 1) {
        int v = (t >= off) ? scanbuf[t - off] : 0;
        __syncthreads();
        scanbuf[t] += v;
        __syncthreads();
    }
    if (t < NB) loff[t] = scanbuf[t] - c;
    if (t == 1023) loff[NB] = scanbuf[1023];
    __syncthreads();

    if (t < NB) {
        int cc = cnt[t];
        gbase[t] = cc ? atomicAdd(&gcur[t], cc) : 0;
    }
    __syncthreads();

#pragma unroll
    for (int j = 0; j < 4; ++j) {
        if (my_ok[j]) {
            int lp = loff[my_b[j]] + my_rank[j];
            pay[lp] = make_uint2(my_p[j], __float_as_uint(my_v[j]));
            dest16[lp] = (unsigned short)my_b[j];
        }
    }
    __syncthreads();

    int tot = loff[NB];
    for (int i = t; i < tot; i += 1024) {
        int b = dest16[i];
        int go = gbase[b] + (i - loff[b]);
        if (go < CAP) payload[(size_t)b * CAP + go] = pay[i];
        else {
            int op = atomicAdd(ovf_cnt, 1);
            if (op < OVFCAP) {
                unsigned px = pay[i].x;
                ovf[3 * op] = ((unsigned)b << 7) | ((px >> 18) & 127u);
                ovf[3 * op + 1] = px;
                ovf[3 * op + 2] = pay[i].y;
            }
        }
    }
}

// Gather: one block per HALF-bucket (64 rows).  Sweeps the whole bucket's
// payload, filters by row bit 6.  spay 15 KB -> 3 blocks/CU, grid 1564.
__global__ __launch_bounds__(640, 7) void bucket_gather(
    const int* __restrict__ gcur, const uint2* __restrict__ payload,
    const unsigned short* __restrict__ g, float* __restrict__ out) {
    __shared__ unsigned spay[CAPH];
    __shared__ int cnt[64];
    __shared__ int rs[65];
    __shared__ int cur[64];
    __shared__ int sb[64];

    const int t = threadIdx.x;
    const int b = blockIdx.x >> 1;
    const unsigned h = blockIdx.x & 1;
    int n = gcur[b];
    n = (n < CAP) ? n : CAP;

    if (t < 64) cnt[t] = 0;
    __syncthreads();

    const uint2* pb = payload + (size_t)b * CAP;
    const unsigned* pbx = (const unsigned*)pb;
    for (int i = t; i < n; i += 640) {
        unsigned r = (pbx[2 * i] >> 18) & 127u;
        if ((r >> 6) == h) atomicAdd(&cnt[r & 63u], 1);
    }
    __syncthreads();

    if (t < 64) sb[t] = cnt[t];
    __syncthreads();
    for (int off = 1; off < 64; off <<= 1) {
        int v = 0;
        if (t < 64 && t >= off) v = sb[t - off];
        __syncthreads();
        if (t < 64) sb[t] += v;
        __syncthreads();
    }
    if (t < 64) { int e = sb[t] - cnt[t]; rs[t] = e; cur[t] = e; }
    if (t == 0) rs[64] = 0;   // patched below
    __syncthreads();
    if (t == 63) rs[64] = sb[63];
    __syncthreads();

    for (int i = t; i < n; i += 640) {
        uint2 p = pb[i];
        unsigned r = (p.x >> 18) & 127u;
        if ((r >> 6) == h) {
            unsigned q = (unsigned)(__uint_as_float(p.y) * 16383.f + 0.5f);
            int pos = atomicAdd(&cur[r & 63u], 1);
            if (pos < CAPH) spay[pos] = (p.x & 0x3FFFFu) | (q << 18);
            else {  // never expected: direct slow-path
                unsigned s = ((unsigned)b << 7) | r;
                unsigned base = (p.x & 0x1FFFFu) * 40u + ((p.x >> 17) & 1u) * GEL;
                float v = __uint_as_float(p.y);
                for (int cch = 0; cch < 40; ++cch)
                    unsafeAtomicAdd(out + s * 40 + cch, v * bf2f(g[base + cch]));
            }
        }
    }
    __syncthreads();

    const int le = t / 10;
    const int q4 = (t - le * 10) * 4;
    const float VS = 1.0f / 16383.0f;
    int e0 = rs[le], e1 = rs[le + 1];
    e1 = (e1 < CAPH) ? e1 : CAPH;
    float4 a0 = make_float4(0.f, 0.f, 0.f, 0.f);
    float4 a1 = make_float4(0.f, 0.f, 0.f, 0.f);
    int e = e0;
    for (; e + 4 <= e1; e += 4) {
        unsigned p0 = spay[e], p1 = spay[e + 1], p2 = spay[e + 2], p3 = spay[e + 3];
        ushort4 u0 = *(const ushort4*)(g + (p0 & 0x1FFFFu) * 40u + ((p0 >> 17) & 1u) * GEL + q4);
        ushort4 u1 = *(const ushort4*)(g + (p1 & 0x1FFFFu) * 40u + ((p1 >> 17) & 1u) * GEL + q4);
        ushort4 u2 = *(const ushort4*)(g + (p2 & 0x1FFFFu) * 40u + ((p2 >> 17) & 1u) * GEL + q4);
        ushort4 u3 = *(const ushort4*)(g + (p3 & 0x1FFFFu) * 40u + ((p3 >> 17) & 1u) * GEL + q4);
        float v0 = (float)(p0 >> 18) * VS, v1 = (float)(p1 >> 18) * VS;
        float v2 = (float)(p2 >> 18) * VS, v3 = (float)(p3 >> 18) * VS;
        a0.x = fmaf(v0, bf2f(u0.x), a0.x); a0.y = fmaf(v0, bf2f(u0.y), a0.y);
        a0.z = fmaf(v0, bf2f(u0.z), a0.z); a0.w = fmaf(v0, bf2f(u0.w), a0.w);
        a1.x = fmaf(v1, bf2f(u1.x), a1.x); a1.y = fmaf(v1, bf2f(u1.y), a1.y);
        a1.z = fmaf(v1, bf2f(u1.z), a1.z); a1.w = fmaf(v1, bf2f(u1.w), a1.w);
        a0.x = fmaf(v2, bf2f(u2.x), a0.x); a0.y = fmaf(v2, bf2f(u2.y), a0.y);
        a0.z = fmaf(v2, bf2f(u2.z), a0.z); a0.w = fmaf(v2, bf2f(u2.w), a0.w);
        a1.x = fmaf(v3, bf2f(u3.x), a1.x); a1.y = fmaf(v3, bf2f(u3.y), a1.y);
        a1.z = fmaf(v3, bf2f(u3.z), a1.z); a1.w = fmaf(v3, bf2f(u3.w), a1.w);
    }
    for (; e < e1; ++e) {
        unsigned p = spay[e];
        float v = (float)(p >> 18) * VS;
        ushort4 u = *(const ushort4*)(g + (p & 0x1FFFFu) * 40u + ((p >> 17) & 1u) * GEL + q4);
        a0.x = fmaf(v, bf2f(u.x), a0.x); a0.y = fmaf(v, bf2f(u.y), a0.y);
        a0.z = fmaf(v, bf2f(u.z), a0.z); a0.w = fmaf(v, bf2f(u.w), a0.w);
    }
    int gr = b * 128 + h * 64 + le;
    if (gr < Nn && e1 > e0) {
        float* po = out + gr * 40 + q4;
        float4 o = *(float4*)po;
        o.x += a0.x + a1.x; o.y += a0.y + a1.y;
        o.z += a0.z + a1.z; o.w += a0.w + a1.w;
        *(float4*)po = o;
    }
}

// Slow-path for (expected-zero) bucket overflow.
__global__ __launch_bounds__(256) void ovf_scatter(
    const int* __restrict__ ovf_cnt, const unsigned* __restrict__ ovf,
    const unsigned short* __restrict__ g, float* __restrict__ out) {
    int n = *ovf_cnt;
    n = (n < OVFCAP) ? n : OVFCAP;
    int total = n * 40;
    for (int i = blockIdx.x * 256 + threadIdx.x; i < total; i += 2048) {
        int idx = i / 40, c = i % 40;
        unsigned s = ovf[3 * idx];
        unsigned p = ovf[3 * idx + 1];
        float v = __uint_as_float(ovf[3 * idx + 2]);
        unsigned dst = p & 0x1FFFFu;
        unsigned gph = (p >> 17) & 1u;
        float gf = bf2f(g[gph * GEL + dst * 40 + c]);
        unsafeAtomicAdd(out + s * 40 + c, v * gf);
    }
}

extern "C" void kernel_launch(void* const* d_in, const int* in_sizes, int n_in,
                              void* d_out, int out_size, void* d_ws, size_t ws_size,
                              hipStream_t stream) {
    const float* x        = (const float*)d_in[0];
    const int*   adj_src  = (const int*)d_in[2];
    const int*   adj_dst  = (const int*)d_in[3];
    const float* adj_val  = (const float*)d_in[4];
    const int*   adj2_src = (const int*)d_in[5];
    const int*   adj2_dst = (const int*)d_in[6];
    const float* adj2_val = (const float*)d_in[7];
    const float* fc1_w    = (const float*)d_in[8];
    const float* fc_out_w = (const float*)d_in[9];
    const float* fc_out_b = (const float*)d_in[10];
    float* out = (float*)d_out;

    char* ws = (char*)d_ws;
    unsigned short* Mb      = (unsigned short*)(ws + MP_OFF);
    unsigned short* g       = (unsigned short*)(ws + G_OFF);
    int*            gcur    = (int*)(ws + GCUR_OFF);
    int*            ovf_cnt = (int*)(ws + OVFC_OFF);
    unsigned*       ovf     = (unsigned*)(ws + OVFL_OFF);
    uint2*          payload = (uint2*)(ws + PAY_OFF);

    const int E1 = in_sizes[2];
    const int E2 = in_sizes[5];
    const int Etot = E1 + E2;

    make_M<<<128, 256, 0, stream>>>(fc1_w, fc_out_w, Mb);
    gemm_mfma<<<(Nn + 127) / 128, 512, 0, stream>>>(x, Mb, fc_out_b, out, g);

    hipMemsetAsync(gcur, 0, NB * sizeof(int) + 16, stream);  // gcur + ovf_cnt
    partition<<<(Etot + CHUNK - 1) / CHUNK, 1024, 0, stream>>>(
        adj_src, adj_dst, adj_val, E1, adj2_src, adj2_dst, adj2_val, E2,
        gcur, payload, ovf_cnt, ovf);
    bucket_gather<<<NB * 2, 640, 0, stream>>>(gcur, payload, g, out);
    ovf_scatter<<<8, 256, 0, stream>>>(ovf_cnt, ovf, g, out);
}